// Round 1
// baseline (372.158 us; speedup 1.0000x reference)
//
#include <hip/hip_runtime.h>
#include <math.h>

#define BB 128
#define TT 2048
#define OO 128
#define EE 512
#define LL 34
#define XDIM 640      // O+E
#define CHUNKS 8
#define CHUNK_LEN 256 // TT / CHUNKS
#define PSTRIDE 132   // per-(b,chunk) partial record: 128 c + S + M (+pad)

__device__ __forceinline__ float sigmoidf_(float x) { return 1.0f / (1.0f + __expf(-x)); }

// ---------------- K1: LSTM cell. 2 batch rows per block, one thread per gate.
__global__ __launch_bounds__(512) void lstm_kernel(
    const float* __restrict__ y1, const float* __restrict__ c1,
    const float* __restrict__ sh1, const float* __restrict__ sc1,
    const float* __restrict__ Wih, const float* __restrict__ bih,
    const float* __restrict__ Whh, const float* __restrict__ bhh,
    float* __restrict__ out_sh, float* __restrict__ out_sc)
{
    __shared__ float x0[768], x1[768];   // [y1(512) | c1(128) | sh1(128)]
    __shared__ float g0[512], g1[512];
    const int tid = threadIdx.x;
    const int b0 = blockIdx.x * 2, b1v = b0 + 1;

    x0[tid] = y1[b0 * EE + tid];
    x1[tid] = y1[b1v * EE + tid];
    if (tid < 128) {
        x0[512 + tid] = c1[b0 * OO + tid];
        x1[512 + tid] = c1[b1v * OO + tid];
        x0[640 + tid] = sh1[b0 * OO + tid];
        x1[640 + tid] = sh1[b1v * OO + tid];
    }
    __syncthreads();

    float a0 = bih[tid] + bhh[tid];
    float a1 = a0;
    const float* wr = Wih + (size_t)tid * XDIM;
    #pragma unroll 8
    for (int k = 0; k < XDIM; k += 4) {
        float4 w = *(const float4*)(wr + k);
        a0 += w.x * x0[k] + w.y * x0[k + 1] + w.z * x0[k + 2] + w.w * x0[k + 3];
        a1 += w.x * x1[k] + w.y * x1[k + 1] + w.z * x1[k + 2] + w.w * x1[k + 3];
    }
    const float* wh = Whh + (size_t)tid * OO;
    #pragma unroll 8
    for (int k = 0; k < OO; k += 4) {
        float4 w = *(const float4*)(wh + k);
        a0 += w.x * x0[640 + k] + w.y * x0[641 + k] + w.z * x0[642 + k] + w.w * x0[643 + k];
        a1 += w.x * x1[640 + k] + w.y * x1[641 + k] + w.z * x1[642 + k] + w.w * x1[643 + k];
    }
    g0[tid] = a0;
    g1[tid] = a1;
    __syncthreads();

    if (tid < 256) {
        const int o = tid & 127;
        const int b = (tid < 128) ? b0 : b1v;
        const float* g = (tid < 128) ? g0 : g1;
        // PyTorch gate order: i, f, g, o
        float gi = g[o], gf = g[o + 128], gg = g[o + 256], go = g[o + 384];
        float sc = sigmoidf_(gf) * sc1[b * OO + o] + sigmoidf_(gi) * tanhf(gg);
        float sh = sigmoidf_(go) * tanhf(sc);
        out_sc[b * OO + o] = sc;
        out_sh[b * OO + o] = sh;
    }
}

// ---------------- K2: fused attention (flash-style online softmax), per-chunk partials.
__global__ __launch_bounds__(256) void attn_kernel(
    const float* __restrict__ hk, const float* __restrict__ hv,
    const float* __restrict__ mask, const float* __restrict__ sc,
    float* __restrict__ ws_part)
{
    const int b = blockIdx.y;
    const int chunk = blockIdx.x;
    const int tid = threadIdx.x;
    const int g = tid >> 5, l = tid & 31;   // 8 groups x 32 lanes, lane -> o-slice

    const float4 scv = *(const float4*)(sc + b * OO + l * 4);
    float m = -INFINITY, S = 0.f;
    float4 acc = make_float4(0.f, 0.f, 0.f, 0.f);

    const float* kbase = hk + (size_t)(b * TT + chunk * CHUNK_LEN) * OO;
    const float* vbase = hv + (size_t)(b * TT + chunk * CHUNK_LEN) * OO;
    const float* mbase = mask + (size_t)b * TT + chunk * CHUNK_LEN;

    for (int r = g; r < CHUNK_LEN; r += 8) {
        float4 kv = *(const float4*)(kbase + (size_t)r * OO + l * 4);
        float part = kv.x * scv.x + kv.y * scv.y + kv.z * scv.z + kv.w * scv.w;
        // butterfly over the 32 lanes of this group (masks <32 stay in-half on wave64)
        part += __shfl_xor(part, 16);
        part += __shfl_xor(part, 8);
        part += __shfl_xor(part, 4);
        part += __shfl_xor(part, 2);
        part += __shfl_xor(part, 1);
        float mk = mbase[r];
        float4 vv = *(const float4*)(vbase + (size_t)r * OO + l * 4);
        float mnew = fmaxf(m, part);
        float scale = __expf(m - mnew);      // exp(-inf)=0 on first iter
        float p = __expf(part - mnew) * mk;  // mask folds in; identical to ref math
        S = S * scale + p;
        acc.x = acc.x * scale + p * vv.x;
        acc.y = acc.y * scale + p * vv.y;
        acc.z = acc.z * scale + p * vv.z;
        acc.w = acc.w * scale + p * vv.w;
        m = mnew;
    }

    __shared__ float sm[8], sS[8], sacc[8][128];
    if (l == 0) { sm[g] = m; sS[g] = S; }
    sacc[g][l * 4 + 0] = acc.x;
    sacc[g][l * 4 + 1] = acc.y;
    sacc[g][l * 4 + 2] = acc.z;
    sacc[g][l * 4 + 3] = acc.w;
    __syncthreads();

    float M = sm[0];
    #pragma unroll
    for (int i = 1; i < 8; i++) M = fmaxf(M, sm[i]);

    float* wout = ws_part + (size_t)(b * CHUNKS + chunk) * PSTRIDE;
    if (tid < 128) {
        float ca = 0.f;
        #pragma unroll
        for (int i = 0; i < 8; i++) ca += sacc[i][tid] * __expf(sm[i] - M);
        wout[tid] = ca;
    } else if (tid == 128) {
        float St = 0.f;
        #pragma unroll
        for (int i = 0; i < 8; i++) St += sS[i] * __expf(sm[i] - M);
        wout[128] = St;
        wout[129] = M;
    }
}

// ---------------- K3: combine chunk partials -> c, then MLP head + softmax.
__global__ __launch_bounds__(128) void final_kernel(
    const float* __restrict__ ws_part, const float* __restrict__ sh_in,
    const float* __restrict__ W1, const float* __restrict__ b1,
    const float* __restrict__ W2, const float* __restrict__ b2,
    const float* __restrict__ W3, const float* __restrict__ b3,
    float* __restrict__ out_p, float* __restrict__ out_c)
{
    const int b = blockIdx.x, tid = threadIdx.x;
    __shared__ float sM[8], sS[8], cbuf[128], shbuf[128], h1[LL], zz[LL], red2[2];
    const float* base = ws_part + (size_t)b * CHUNKS * PSTRIDE;

    if (tid < 8) {
        sS[tid] = base[tid * PSTRIDE + 128];
        sM[tid] = base[tid * PSTRIDE + 129];
    }
    __syncthreads();
    float M = sM[0];
    #pragma unroll
    for (int i = 1; i < 8; i++) M = fmaxf(M, sM[i]);

    {
        float ca = 0.f, S = 0.f;
        #pragma unroll
        for (int i = 0; i < 8; i++) {
            float e = __expf(sM[i] - M);
            ca += base[i * PSTRIDE + tid] * e;
            S += sS[i] * e;
        }
        float cv = ca / S;
        cbuf[tid] = cv;
        out_c[b * OO + tid] = cv;
        shbuf[tid] = sh_in[b * OO + tid];
    }
    __syncthreads();

    if (tid < LL) {
        float a = b1[tid] + b2[tid];
        const float* w1r = W1 + tid * OO;
        const float* w2r = W2 + tid * OO;
        #pragma unroll 4
        for (int k = 0; k < OO; k++) a += w1r[k] * shbuf[k] + w2r[k] * cbuf[k];
        h1[tid] = fmaxf(a, 0.f);
    }
    __syncthreads();
    if (tid < LL) {
        float z = b3[tid];
        const float* w3r = W3 + tid * LL;
        for (int k = 0; k < LL; k++) z += w3r[k] * h1[k];
        zz[tid] = z;
    }
    __syncthreads();
    if (tid == 0) {
        float mm = zz[0];
        for (int i = 1; i < LL; i++) mm = fmaxf(mm, zz[i]);
        float ss = 0.f;
        for (int i = 0; i < LL; i++) ss += __expf(zz[i] - mm);
        red2[0] = mm; red2[1] = ss;
    }
    __syncthreads();
    if (tid < LL) out_p[b * LL + tid] = __expf(zz[tid] - red2[0]) / red2[1];
}

extern "C" void kernel_launch(void* const* d_in, const int* in_sizes, int n_in,
                              void* d_out, int out_size, void* d_ws, size_t ws_size,
                              hipStream_t stream) {
    (void)in_sizes; (void)n_in; (void)out_size; (void)ws_size;
    const float* hk   = (const float*)d_in[0];
    const float* hv   = (const float*)d_in[1];
    const float* y1   = (const float*)d_in[2];
    const float* c1   = (const float*)d_in[3];
    const float* sh1  = (const float*)d_in[4];
    const float* sc1  = (const float*)d_in[5];
    const float* mask = (const float*)d_in[6];
    const float* Wih  = (const float*)d_in[7];
    const float* bih  = (const float*)d_in[8];
    const float* Whh  = (const float*)d_in[9];
    const float* bhh  = (const float*)d_in[10];
    const float* W1   = (const float*)d_in[11];
    const float* b1   = (const float*)d_in[12];
    const float* W2   = (const float*)d_in[13];
    const float* b2   = (const float*)d_in[14];
    const float* W3   = (const float*)d_in[15];
    const float* b3   = (const float*)d_in[16];

    float* out    = (float*)d_out;        // [B, L]
    float* out_c  = out + BB * LL;        // [B, O] @ 4352
    float* out_sh = out_c + BB * OO;      // [B, O] @ 20736
    float* out_sc = out_sh + BB * OO;     // [B, O] @ 37120
    float* ws_part = (float*)d_ws;        // [B*CHUNKS, PSTRIDE] = 540 KB

    lstm_kernel<<<BB / 2, 512, 0, stream>>>(y1, c1, sh1, sc1, Wih, bih, Whh, bhh,
                                            out_sh, out_sc);
    attn_kernel<<<dim3(CHUNKS, BB), 256, 0, stream>>>(hk, hv, mask, out_sc, ws_part);
    final_kernel<<<BB, 128, 0, stream>>>(ws_part, out_sh, W1, b1, W2, b2, W3, b3,
                                         out, out_c);
}

// Round 2
// 336.594 us; speedup vs baseline: 1.1057x; 1.1057x over previous
//
#include <hip/hip_runtime.h>
#include <math.h>

#define BB 128
#define TT 2048
#define OO 128
#define EE 512
#define LL 34
#define XDIM 640       // O+E
#define CHUNKS 16
#define CHUNK_LEN 128  // TT / CHUNKS
#define PSTRIDE 132    // per-(b,chunk) partial record: 128 c + S + M (+pad)
#define GWS_FLOATS (BB * 4 * OO)   // staged gates [B, 512]

__device__ __forceinline__ float sigmoidf_(float x) { return 1.0f / (1.0f + __expf(-x)); }

__device__ __forceinline__ float hred32(float x) {
    x += __shfl_xor(x, 16);
    x += __shfl_xor(x, 8);
    x += __shfl_xor(x, 4);
    x += __shfl_xor(x, 2);
    x += __shfl_xor(x, 1);
    return x;
}

// ---------------- K1a: LSTM gate GEMM, coalesced lane-split-k.
// grid (4 gate-tiles, 32 batch-quads) x 256 threads. 4 batch rows share each W load.
__global__ __launch_bounds__(256) void lstm_gemm_kernel(
    const float* __restrict__ y1, const float* __restrict__ c1,
    const float* __restrict__ sh1,
    const float* __restrict__ Wih, const float* __restrict__ bih,
    const float* __restrict__ Whh, const float* __restrict__ bhh,
    float* __restrict__ gws)
{
    __shared__ float xs[4][768];   // per batch row: [y1(512) | c1(128) | sh1(128)]
    const int tid = threadIdx.x;
    const int t = blockIdx.x;          // gate tile: rows [t*128, t*128+128)
    const int qb = blockIdx.y * 4;     // batch quad base

    for (int idx = tid; idx < 4 * 768; idx += 256) {
        int bi = idx / 768, k = idx - bi * 768;
        int b = qb + bi;
        float v;
        if (k < 512)      v = y1[b * EE + k];
        else if (k < 640) v = c1[b * OO + (k - 512)];
        else              v = sh1[b * OO + (k - 640)];
        xs[bi][k] = v;
    }
    __syncthreads();

    const int w = tid >> 6, l = tid & 63;
    for (int i = 0; i < 32; ++i) {
        const int row = t * 128 + w * 32 + i;
        const float* wr = Wih + (size_t)row * XDIM;
        float a0 = 0.f, a1 = 0.f, a2 = 0.f, a3 = 0.f;
        #pragma unroll
        for (int j = 0; j < 10; ++j) {
            float wv = wr[l + 64 * j];
            a0 += wv * xs[0][l + 64 * j];
            a1 += wv * xs[1][l + 64 * j];
            a2 += wv * xs[2][l + 64 * j];
            a3 += wv * xs[3][l + 64 * j];
        }
        const float* wh = Whh + (size_t)row * OO;
        #pragma unroll
        for (int j = 0; j < 2; ++j) {
            float wv = wh[l + 64 * j];
            a0 += wv * xs[0][640 + l + 64 * j];
            a1 += wv * xs[1][640 + l + 64 * j];
            a2 += wv * xs[2][640 + l + 64 * j];
            a3 += wv * xs[3][640 + l + 64 * j];
        }
        #pragma unroll
        for (int off = 32; off >= 1; off >>= 1) {
            a0 += __shfl_xor(a0, off);
            a1 += __shfl_xor(a1, off);
            a2 += __shfl_xor(a2, off);
            a3 += __shfl_xor(a3, off);
        }
        if (l == 0) {
            float bb = bih[row] + bhh[row];
            gws[(size_t)(qb + 0) * 512 + row] = a0 + bb;
            gws[(size_t)(qb + 1) * 512 + row] = a1 + bb;
            gws[(size_t)(qb + 2) * 512 + row] = a2 + bb;
            gws[(size_t)(qb + 3) * 512 + row] = a3 + bb;
        }
    }
}

// ---------------- K1b: gate nonlinearity -> sc, sh.
__global__ __launch_bounds__(128) void lstm_act_kernel(
    const float* __restrict__ gws, const float* __restrict__ sc1,
    float* __restrict__ out_sh, float* __restrict__ out_sc)
{
    const int b = blockIdx.x, o = threadIdx.x;
    const float* g = gws + (size_t)b * 512;
    float gi = g[o], gf = g[o + 128], gg = g[o + 256], go = g[o + 384];
    float sc = sigmoidf_(gf) * sc1[b * OO + o] + sigmoidf_(gi) * tanhf(gg);
    float sh = sigmoidf_(go) * tanhf(sc);
    out_sc[b * OO + o] = sc;
    out_sh[b * OO + o] = sh;
}

// ---------------- K2: fused attention, flash-style online softmax, chunk partials.
__global__ __launch_bounds__(256) void attn_kernel(
    const float* __restrict__ hk, const float* __restrict__ hv,
    const float* __restrict__ mask, const float* __restrict__ sc,
    float* __restrict__ ws_part)
{
    const int b = blockIdx.y;
    const int chunk = blockIdx.x;
    const int tid = threadIdx.x;
    const int g = tid >> 5, l = tid & 31;   // 8 groups x 32 lanes; group owns 16 contiguous rows

    const float4 scv = *(const float4*)(sc + b * OO + l * 4);
    float m = -INFINITY, S = 0.f;
    float4 acc = make_float4(0.f, 0.f, 0.f, 0.f);

    const float* kbase = hk + (size_t)(b * TT + chunk * CHUNK_LEN) * OO;
    const float* vbase = hv + (size_t)(b * TT + chunk * CHUNK_LEN) * OO;
    const float* mbase = mask + (size_t)b * TT + chunk * CHUNK_LEN;

    #pragma unroll 1
    for (int q = 0; q < 4; ++q) {
        const int r = g * 16 + q * 4;
        const float4 mk = *(const float4*)(mbase + r);
        if (mk.x == 0.f) break;   // mask is a contiguous prefix of 1s
        // issue all 8 row loads before any reduction
        const float4 k0 = *(const float4*)(kbase + (size_t)(r + 0) * OO + l * 4);
        const float4 k1 = *(const float4*)(kbase + (size_t)(r + 1) * OO + l * 4);
        const float4 k2 = *(const float4*)(kbase + (size_t)(r + 2) * OO + l * 4);
        const float4 k3 = *(const float4*)(kbase + (size_t)(r + 3) * OO + l * 4);
        const float4 v0 = *(const float4*)(vbase + (size_t)(r + 0) * OO + l * 4);
        const float4 v1 = *(const float4*)(vbase + (size_t)(r + 1) * OO + l * 4);
        const float4 v2 = *(const float4*)(vbase + (size_t)(r + 2) * OO + l * 4);
        const float4 v3 = *(const float4*)(vbase + (size_t)(r + 3) * OO + l * 4);
        float s0 = k0.x * scv.x + k0.y * scv.y + k0.z * scv.z + k0.w * scv.w;
        float s1 = k1.x * scv.x + k1.y * scv.y + k1.z * scv.z + k1.w * scv.w;
        float s2 = k2.x * scv.x + k2.y * scv.y + k2.z * scv.z + k2.w * scv.w;
        float s3 = k3.x * scv.x + k3.y * scv.y + k3.z * scv.z + k3.w * scv.w;
        s0 = hred32(s0); s1 = hred32(s1); s2 = hred32(s2); s3 = hred32(s3);

        float mnew, scale, p;
        mnew = fmaxf(m, s0); scale = __expf(m - mnew); p = __expf(s0 - mnew) * mk.x;
        S = S * scale + p;
        acc.x = acc.x * scale + p * v0.x; acc.y = acc.y * scale + p * v0.y;
        acc.z = acc.z * scale + p * v0.z; acc.w = acc.w * scale + p * v0.w;
        m = mnew;
        mnew = fmaxf(m, s1); scale = __expf(m - mnew); p = __expf(s1 - mnew) * mk.y;
        S = S * scale + p;
        acc.x = acc.x * scale + p * v1.x; acc.y = acc.y * scale + p * v1.y;
        acc.z = acc.z * scale + p * v1.z; acc.w = acc.w * scale + p * v1.w;
        m = mnew;
        mnew = fmaxf(m, s2); scale = __expf(m - mnew); p = __expf(s2 - mnew) * mk.z;
        S = S * scale + p;
        acc.x = acc.x * scale + p * v2.x; acc.y = acc.y * scale + p * v2.y;
        acc.z = acc.z * scale + p * v2.z; acc.w = acc.w * scale + p * v2.w;
        m = mnew;
        mnew = fmaxf(m, s3); scale = __expf(m - mnew); p = __expf(s3 - mnew) * mk.w;
        S = S * scale + p;
        acc.x = acc.x * scale + p * v3.x; acc.y = acc.y * scale + p * v3.y;
        acc.z = acc.z * scale + p * v3.z; acc.w = acc.w * scale + p * v3.w;
        m = mnew;
    }

    __shared__ float sm[8], sS[8], sacc[8][128];
    if (l == 0) { sm[g] = m; sS[g] = S; }
    sacc[g][l * 4 + 0] = acc.x;
    sacc[g][l * 4 + 1] = acc.y;
    sacc[g][l * 4 + 2] = acc.z;
    sacc[g][l * 4 + 3] = acc.w;
    __syncthreads();

    float M = sm[0];
    #pragma unroll
    for (int i = 1; i < 8; i++) M = fmaxf(M, sm[i]);
    const float Mc = (M == -INFINITY) ? 0.f : M;   // all-masked chunk: avoid inf-inf

    float* wout = ws_part + (size_t)(b * CHUNKS + chunk) * PSTRIDE;
    if (tid < 128) {
        float ca = 0.f;
        #pragma unroll
        for (int i = 0; i < 8; i++) ca += sacc[i][tid] * __expf(sm[i] - Mc);
        wout[tid] = ca;
    } else if (tid == 128) {
        float St = 0.f;
        #pragma unroll
        for (int i = 0; i < 8; i++) St += sS[i] * __expf(sm[i] - Mc);
        wout[128] = St;
        wout[129] = M;   // true M (-inf if chunk fully masked -> contributes 0 downstream)
    }
}

// ---------------- K3: combine chunk partials -> c, then MLP head + softmax.
__global__ __launch_bounds__(256) void final_kernel(
    const float* __restrict__ ws_part, const float* __restrict__ sh_in,
    const float* __restrict__ W1, const float* __restrict__ b1,
    const float* __restrict__ W2, const float* __restrict__ b2,
    const float* __restrict__ W3, const float* __restrict__ b3,
    float* __restrict__ out_p, float* __restrict__ out_c)
{
    const int b = blockIdx.x, tid = threadIdx.x;
    __shared__ float sM[CHUNKS], sS[CHUNKS], cbuf[128], shbuf[128], h1[LL], zz[LL], red2[2];
    const float* base = ws_part + (size_t)b * CHUNKS * PSTRIDE;

    if (tid < CHUNKS) {
        sS[tid] = base[tid * PSTRIDE + 128];
        sM[tid] = base[tid * PSTRIDE + 129];
    }
    __syncthreads();
    float M = sM[0];
    #pragma unroll
    for (int i = 1; i < CHUNKS; i++) M = fmaxf(M, sM[i]);

    if (tid < 128) {
        float ca = 0.f, S = 0.f;
        #pragma unroll
        for (int i = 0; i < CHUNKS; i++) {
            float e = __expf(sM[i] - M);   // sM[i] = -inf -> 0
            ca += base[i * PSTRIDE + tid] * e;
            S += sS[i] * e;
        }
        float cv = ca / S;
        cbuf[tid] = cv;
        out_c[b * OO + tid] = cv;
        shbuf[tid] = sh_in[b * OO + tid];
    }
    __syncthreads();

    // h1 = relu(sh@W1.T + b1 + c@W2.T + b2): quad (4 lanes) per output, coalesced 16B reads
    const int o = tid >> 2, l2 = tid & 3;
    if (o < LL) {
        float a = 0.f;
        const float* w1r = W1 + o * OO;
        const float* w2r = W2 + o * OO;
        #pragma unroll 8
        for (int j = 0; j < 32; ++j) {
            int k = l2 + 4 * j;
            a += w1r[k] * shbuf[k] + w2r[k] * cbuf[k];
        }
        a += __shfl_xor(a, 1);
        a += __shfl_xor(a, 2);
        if (l2 == 0) h1[o] = fmaxf(a + b1[o] + b2[o], 0.f);
    }
    __syncthreads();

    if (o < LL) {
        float z = 0.f;
        const float* w3r = W3 + o * LL;
        for (int j = 0; j < 9; ++j) {
            int k = l2 + 4 * j;
            if (k < LL) z += w3r[k] * h1[k];
        }
        z += __shfl_xor(z, 1);
        z += __shfl_xor(z, 2);
        if (l2 == 0) zz[o] = z + b3[o];
    }
    __syncthreads();
    if (tid == 0) {
        float mm = zz[0];
        for (int i = 1; i < LL; i++) mm = fmaxf(mm, zz[i]);
        float ss = 0.f;
        for (int i = 0; i < LL; i++) ss += __expf(zz[i] - mm);
        red2[0] = mm; red2[1] = ss;
    }
    __syncthreads();
    if (tid < LL) out_p[b * LL + tid] = __expf(zz[tid] - red2[0]) / red2[1];
}

extern "C" void kernel_launch(void* const* d_in, const int* in_sizes, int n_in,
                              void* d_out, int out_size, void* d_ws, size_t ws_size,
                              hipStream_t stream) {
    (void)in_sizes; (void)n_in; (void)out_size; (void)ws_size;
    const float* hk   = (const float*)d_in[0];
    const float* hv   = (const float*)d_in[1];
    const float* y1   = (const float*)d_in[2];
    const float* c1   = (const float*)d_in[3];
    const float* sh1  = (const float*)d_in[4];
    const float* sc1  = (const float*)d_in[5];
    const float* mask = (const float*)d_in[6];
    const float* Wih  = (const float*)d_in[7];
    const float* bih  = (const float*)d_in[8];
    const float* Whh  = (const float*)d_in[9];
    const float* bhh  = (const float*)d_in[10];
    const float* W1   = (const float*)d_in[11];
    const float* b1   = (const float*)d_in[12];
    const float* W2   = (const float*)d_in[13];
    const float* b2   = (const float*)d_in[14];
    const float* W3   = (const float*)d_in[15];
    const float* b3   = (const float*)d_in[16];

    float* out    = (float*)d_out;        // [B, L]
    float* out_c  = out + BB * LL;        // [B, O]
    float* out_sh = out_c + BB * OO;      // [B, O]
    float* out_sc = out_sh + BB * OO;     // [B, O]

    float* gws     = (float*)d_ws;                 // [B, 512] staged gates (256 KB)
    float* ws_part = gws + GWS_FLOATS;             // [B*CHUNKS, PSTRIDE] (~1.03 MB)

    lstm_gemm_kernel<<<dim3(4, 32), 256, 0, stream>>>(y1, c1, sh1, Wih, bih, Whh, bhh, gws);
    lstm_act_kernel<<<BB, 128, 0, stream>>>(gws, sc1, out_sh, out_sc);
    attn_kernel<<<dim3(CHUNKS, BB), 256, 0, stream>>>(hk, hv, mask, out_sc, ws_part);
    final_kernel<<<BB, 256, 0, stream>>>(ws_part, out_sh, W1, b1, W2, b2, W3, b3,
                                         out, out_c);
}

// Round 3
// 331.216 us; speedup vs baseline: 1.1236x; 1.0162x over previous
//
#include <hip/hip_runtime.h>
#include <math.h>

#define BB 128
#define TT 2048
#define OO 128
#define EE 512
#define LL 34
#define XDIM 640       // O+E
#define CHUNKS 16
#define CHUNK_LEN 128  // TT / CHUNKS

__device__ __forceinline__ float sigmoidf_(float x) { return 1.0f / (1.0f + __expf(-x)); }

// ---------------- K1: LSTM cell, fused GEMM + activation.
// grid (8 o-tiles of 16, 32 batch-quads) = 256 blocks x 256 threads.
// wave g computes gate g for 16 outputs x 4 batches (split-64 dot + butterfly).
__global__ __launch_bounds__(256) void lstm_kernel(
    const float* __restrict__ y1, const float* __restrict__ c1,
    const float* __restrict__ sh1, const float* __restrict__ sc1,
    const float* __restrict__ Wih, const float* __restrict__ bih,
    const float* __restrict__ Whh, const float* __restrict__ bhh,
    float* __restrict__ out_sh, float* __restrict__ out_sc)
{
    __shared__ float xs[4][768];          // per batch row: [y1(512)|c1(128)|sh1(128)]
    __shared__ float gbuf[4][4][16];      // [gate][bi][o_local]
    const int tid = threadIdx.x;
    const int otile = blockIdx.x;         // outputs [otile*16, otile*16+16)
    const int qb = blockIdx.y * 4;        // batch quad base

    for (int idx = tid; idx < 4 * 768; idx += 256) {
        int bi = idx / 768, k = idx - bi * 768;
        int b = qb + bi;
        float v;
        if (k < 512)      v = y1[b * EE + k];
        else if (k < 640) v = c1[b * OO + (k - 512)];
        else              v = sh1[b * OO + (k - 640)];
        xs[bi][k] = v;
    }
    __syncthreads();

    const int g = tid >> 6, l = tid & 63;   // wave g = gate g
    #pragma unroll 2
    for (int i = 0; i < 16; ++i) {
        const int row = g * 128 + otile * 16 + i;
        const float* wr = Wih + (size_t)row * XDIM;
        float a0 = 0.f, a1 = 0.f, a2 = 0.f, a3 = 0.f;
        #pragma unroll
        for (int j = 0; j < 10; ++j) {
            float wv = wr[l + 64 * j];
            a0 += wv * xs[0][l + 64 * j];
            a1 += wv * xs[1][l + 64 * j];
            a2 += wv * xs[2][l + 64 * j];
            a3 += wv * xs[3][l + 64 * j];
        }
        const float* wh = Whh + (size_t)row * OO;
        #pragma unroll
        for (int j = 0; j < 2; ++j) {
            float wv = wh[l + 64 * j];
            a0 += wv * xs[0][640 + l + 64 * j];
            a1 += wv * xs[1][640 + l + 64 * j];
            a2 += wv * xs[2][640 + l + 64 * j];
            a3 += wv * xs[3][640 + l + 64 * j];
        }
        #pragma unroll
        for (int off = 32; off >= 1; off >>= 1) {
            a0 += __shfl_xor(a0, off);
            a1 += __shfl_xor(a1, off);
            a2 += __shfl_xor(a2, off);
            a3 += __shfl_xor(a3, off);
        }
        if (l == 0) {
            float bb = bih[row] + bhh[row];
            gbuf[g][0][i] = a0 + bb;
            gbuf[g][1][i] = a1 + bb;
            gbuf[g][2][i] = a2 + bb;
            gbuf[g][3][i] = a3 + bb;
        }
    }
    __syncthreads();

    if (tid < 64) {
        const int bi = tid >> 4, ol = tid & 15;
        const int b = qb + bi, o = otile * 16 + ol;
        float gi = gbuf[0][bi][ol], gf = gbuf[1][bi][ol];
        float gg = gbuf[2][bi][ol], go = gbuf[3][bi][ol];
        float sc = sigmoidf_(gf) * sc1[b * OO + o] + sigmoidf_(gi) * tanhf(gg);
        float sh = sigmoidf_(go) * tanhf(sc);
        out_sc[b * OO + o] = sc;
        out_sh[b * OO + o] = sh;
    }
}

// ---------------- K2: scores[b,t] = dot(hk[b,t,:], sc[b,:]); masked rows -> 0.
// grid (16 chunks, 128 b) x 256 threads; 16-lane subgroup per row, 8 rows each, full unroll.
__global__ __launch_bounds__(256) void scores_kernel(
    const float* __restrict__ hk, const float* __restrict__ mask,
    const float* __restrict__ sc, float* __restrict__ wbuf)
{
    const int b = blockIdx.y, chunk = blockIdx.x;
    const int tid = threadIdx.x;
    const int sg = tid >> 4, l = tid & 15;   // 16 subgroups x 16 lanes

    const float4 scA = *(const float4*)(sc + b * OO + l * 8);
    const float4 scB = *(const float4*)(sc + b * OO + l * 8 + 4);

    const int r0 = chunk * CHUNK_LEN + sg * 8;
    const float* mrow = mask + (size_t)b * TT + r0;
    const float* krow = hk + ((size_t)b * TT + r0) * OO;

    float s[8];
    #pragma unroll
    for (int i = 0; i < 8; ++i) {
        const bool valid = (mrow[i] != 0.f);
        float4 a = make_float4(0.f, 0.f, 0.f, 0.f);
        float4 c2 = make_float4(0.f, 0.f, 0.f, 0.f);
        if (valid) {
            a  = *(const float4*)(krow + (size_t)i * OO + l * 8);
            c2 = *(const float4*)(krow + (size_t)i * OO + l * 8 + 4);
        }
        s[i] = a.x * scA.x + a.y * scA.y + a.z * scA.z + a.w * scA.w
             + c2.x * scB.x + c2.y * scB.y + c2.z * scB.z + c2.w * scB.w;
    }
    #pragma unroll
    for (int i = 0; i < 8; ++i) {
        s[i] += __shfl_xor(s[i], 8);
        s[i] += __shfl_xor(s[i], 4);
        s[i] += __shfl_xor(s[i], 2);
        s[i] += __shfl_xor(s[i], 1);
    }
    float* wrow = wbuf + (size_t)b * TT + r0;
    #pragma unroll
    for (int i = 0; i < 8; ++i)
        if (l == i) wrow[i] = s[i];
}

// ---------------- K3: per-b masked softmax over scores, in-place -> normalized weights.
__global__ __launch_bounds__(256) void softmax_kernel(
    float* __restrict__ wbuf, const float* __restrict__ mask)
{
    const int b = blockIdx.x, tid = threadIdx.x;
    const int lane = tid & 63, wv = tid >> 6;
    float* srow = wbuf + (size_t)b * TT;
    const float* mrow = mask + (size_t)b * TT;

    float sarr[8], earr[8];
    bool varr[8];
    float lm = -INFINITY;
    #pragma unroll
    for (int j = 0; j < 8; ++j) {
        int t = tid + 256 * j;
        sarr[j] = srow[t];
        varr[j] = (mrow[t] != 0.f);
        if (varr[j]) lm = fmaxf(lm, sarr[j]);
    }
    #pragma unroll
    for (int off = 32; off >= 1; off >>= 1) lm = fmaxf(lm, __shfl_xor(lm, off));
    __shared__ float red[4];
    if (lane == 0) red[wv] = lm;
    __syncthreads();
    const float M = fmaxf(fmaxf(red[0], red[1]), fmaxf(red[2], red[3]));

    float ls = 0.f;
    #pragma unroll
    for (int j = 0; j < 8; ++j) {
        earr[j] = varr[j] ? __expf(sarr[j] - M) : 0.f;
        ls += earr[j];
    }
    #pragma unroll
    for (int off = 32; off >= 1; off >>= 1) ls += __shfl_xor(ls, off);
    __syncthreads();
    if (lane == 0) red[wv] = ls;
    __syncthreads();
    const float inv = 1.f / (red[0] + red[1] + red[2] + red[3]);
    #pragma unroll
    for (int j = 0; j < 8; ++j) srow[tid + 256 * j] = earr[j] * inv;
}

// ---------------- K4: c-partials: ws_c[b,chunk,:] = sum_r w[r] * hv[b,r,:].
// Pure per-lane float4 FMA accumulation; weights broadcast from LDS; zero-weight rows skipped.
__global__ __launch_bounds__(256) void wsum_kernel(
    const float* __restrict__ hv, const float* __restrict__ wbuf,
    float* __restrict__ ws_c)
{
    const int b = blockIdx.y, chunk = blockIdx.x;
    const int tid = threadIdx.x;
    __shared__ float wsh[CHUNK_LEN];
    __shared__ float pacc[8][128];

    if (tid < CHUNK_LEN)
        wsh[tid] = wbuf[(size_t)b * TT + chunk * CHUNK_LEN + tid];
    __syncthreads();

    const int o4 = tid & 31, rr = tid >> 5;   // 8 row-groups x 32 o-quads
    const float* vbase = hv + ((size_t)b * TT + chunk * CHUNK_LEN) * OO + o4 * 4;
    float4 acc = make_float4(0.f, 0.f, 0.f, 0.f);
    #pragma unroll 8
    for (int j = 0; j < 16; ++j) {
        const int r = rr + 8 * j;
        const float wr = wsh[r];
        if (wr != 0.f) {
            float4 v = *(const float4*)(vbase + (size_t)r * OO);
            acc.x += wr * v.x;
            acc.y += wr * v.y;
            acc.z += wr * v.z;
            acc.w += wr * v.w;
        }
    }
    *(float4*)&pacc[rr][o4 * 4] = acc;
    __syncthreads();

    if (tid < 128) {
        float s = 0.f;
        #pragma unroll
        for (int i = 0; i < 8; ++i) s += pacc[i][tid];
        ws_c[((size_t)b * CHUNKS + chunk) * OO + tid] = s;
    }
}

// ---------------- K5: combine chunk partials -> c, then MLP head + softmax.
__global__ __launch_bounds__(256) void final_kernel(
    const float* __restrict__ ws_c, const float* __restrict__ sh_in,
    const float* __restrict__ W1, const float* __restrict__ b1,
    const float* __restrict__ W2, const float* __restrict__ b2,
    const float* __restrict__ W3, const float* __restrict__ b3,
    float* __restrict__ out_p, float* __restrict__ out_c)
{
    const int b = blockIdx.x, tid = threadIdx.x;
    __shared__ float cbuf[128], shbuf[128], h1[LL], zz[LL], red2[2];

    if (tid < 128) {
        float s = 0.f;
        const float* base = ws_c + (size_t)b * CHUNKS * OO + tid;
        #pragma unroll
        for (int i = 0; i < CHUNKS; ++i) s += base[i * OO];
        cbuf[tid] = s;
        out_c[b * OO + tid] = s;
        shbuf[tid] = sh_in[b * OO + tid];
    }
    __syncthreads();

    const int o = tid >> 2, l2 = tid & 3;
    if (o < LL) {
        float a = 0.f;
        const float* w1r = W1 + o * OO;
        const float* w2r = W2 + o * OO;
        #pragma unroll 8
        for (int j = 0; j < 32; ++j) {
            int k = l2 + 4 * j;
            a += w1r[k] * shbuf[k] + w2r[k] * cbuf[k];
        }
        a += __shfl_xor(a, 1);
        a += __shfl_xor(a, 2);
        if (l2 == 0) h1[o] = fmaxf(a + b1[o] + b2[o], 0.f);
    }
    __syncthreads();

    if (o < LL) {
        float z = 0.f;
        const float* w3r = W3 + o * LL;
        for (int j = 0; j < 9; ++j) {
            int k = l2 + 4 * j;
            if (k < LL) z += w3r[k] * h1[k];
        }
        z += __shfl_xor(z, 1);
        z += __shfl_xor(z, 2);
        if (l2 == 0) zz[o] = z + b3[o];
    }
    __syncthreads();
    if (tid == 0) {
        float mm = zz[0];
        for (int i = 1; i < LL; i++) mm = fmaxf(mm, zz[i]);
        float ss = 0.f;
        for (int i = 0; i < LL; i++) ss += __expf(zz[i] - mm);
        red2[0] = mm; red2[1] = ss;
    }
    __syncthreads();
    if (tid < LL) out_p[b * LL + tid] = __expf(zz[tid] - red2[0]) / red2[1];
}

extern "C" void kernel_launch(void* const* d_in, const int* in_sizes, int n_in,
                              void* d_out, int out_size, void* d_ws, size_t ws_size,
                              hipStream_t stream) {
    (void)in_sizes; (void)n_in; (void)out_size; (void)ws_size;
    const float* hk   = (const float*)d_in[0];
    const float* hv   = (const float*)d_in[1];
    const float* y1   = (const float*)d_in[2];
    const float* c1   = (const float*)d_in[3];
    const float* sh1  = (const float*)d_in[4];
    const float* sc1  = (const float*)d_in[5];
    const float* mask = (const float*)d_in[6];
    const float* Wih  = (const float*)d_in[7];
    const float* bih  = (const float*)d_in[8];
    const float* Whh  = (const float*)d_in[9];
    const float* bhh  = (const float*)d_in[10];
    const float* W1   = (const float*)d_in[11];
    const float* b1   = (const float*)d_in[12];
    const float* W2   = (const float*)d_in[13];
    const float* b2   = (const float*)d_in[14];
    const float* W3   = (const float*)d_in[15];
    const float* b3   = (const float*)d_in[16];

    float* out    = (float*)d_out;        // [B, L]
    float* out_c  = out + BB * LL;        // [B, O]
    float* out_sh = out_c + BB * OO;      // [B, O]
    float* out_sc = out_sh + BB * OO;     // [B, O]

    float* wbuf = (float*)d_ws;                    // [B, T] scores -> weights (1 MB)
    float* ws_c = wbuf + (size_t)BB * TT;          // [B, CHUNKS, O] partials (1 MB)

    lstm_kernel<<<dim3(8, 32), 256, 0, stream>>>(y1, c1, sh1, sc1, Wih, bih, Whh, bhh,
                                                 out_sh, out_sc);
    scores_kernel<<<dim3(CHUNKS, BB), 256, 0, stream>>>(hk, mask, out_sc, wbuf);
    softmax_kernel<<<BB, 256, 0, stream>>>(wbuf, mask);
    wsum_kernel<<<dim3(CHUNKS, BB), 256, 0, stream>>>(hv, wbuf, ws_c);
    final_kernel<<<BB, 256, 0, stream>>>(ws_c, out_sh, W1, b1, W2, b2, W3, b3,
                                         out, out_c);
}

// Round 4
// 328.220 us; speedup vs baseline: 1.1339x; 1.0091x over previous
//
#include <hip/hip_runtime.h>
#include <math.h>

#define BB 128
#define TT 2048
#define OO 128
#define EE 512
#define LL 34
#define XDIM 640       // O+E
#define CHUNKS 16
#define CHUNK_LEN 128  // TT / CHUNKS

__device__ __forceinline__ float sigmoidf_(float x) { return 1.0f / (1.0f + __expf(-x)); }

// ---------------- K1: LSTM cell, fused GEMM + activation.
// grid (8 o-tiles of 16, 32 batch-quads) = 256 blocks x 256 threads.
__global__ __launch_bounds__(256) void lstm_kernel(
    const float* __restrict__ y1, const float* __restrict__ c1,
    const float* __restrict__ sh1, const float* __restrict__ sc1,
    const float* __restrict__ Wih, const float* __restrict__ bih,
    const float* __restrict__ Whh, const float* __restrict__ bhh,
    float* __restrict__ out_sh, float* __restrict__ out_sc)
{
    __shared__ float xs[4][768];          // per batch row: [y1(512)|c1(128)|sh1(128)]
    __shared__ float gbuf[4][4][16];      // [gate][bi][o_local]
    const int tid = threadIdx.x;
    const int otile = blockIdx.x;
    const int qb = blockIdx.y * 4;

    for (int idx = tid; idx < 4 * 768; idx += 256) {
        int bi = idx / 768, k = idx - bi * 768;
        int b = qb + bi;
        float v;
        if (k < 512)      v = y1[b * EE + k];
        else if (k < 640) v = c1[b * OO + (k - 512)];
        else              v = sh1[b * OO + (k - 640)];
        xs[bi][k] = v;
    }
    __syncthreads();

    const int g = tid >> 6, l = tid & 63;   // wave g = gate g
    #pragma unroll 2
    for (int i = 0; i < 16; ++i) {
        const int row = g * 128 + otile * 16 + i;
        const float* wr = Wih + (size_t)row * XDIM;
        float a0 = 0.f, a1 = 0.f, a2 = 0.f, a3 = 0.f;
        #pragma unroll
        for (int j = 0; j < 10; ++j) {
            float wv = wr[l + 64 * j];
            a0 += wv * xs[0][l + 64 * j];
            a1 += wv * xs[1][l + 64 * j];
            a2 += wv * xs[2][l + 64 * j];
            a3 += wv * xs[3][l + 64 * j];
        }
        const float* wh = Whh + (size_t)row * OO;
        #pragma unroll
        for (int j = 0; j < 2; ++j) {
            float wv = wh[l + 64 * j];
            a0 += wv * xs[0][640 + l + 64 * j];
            a1 += wv * xs[1][640 + l + 64 * j];
            a2 += wv * xs[2][640 + l + 64 * j];
            a3 += wv * xs[3][640 + l + 64 * j];
        }
        #pragma unroll
        for (int off = 32; off >= 1; off >>= 1) {
            a0 += __shfl_xor(a0, off);
            a1 += __shfl_xor(a1, off);
            a2 += __shfl_xor(a2, off);
            a3 += __shfl_xor(a3, off);
        }
        if (l == 0) {
            float bb = bih[row] + bhh[row];
            gbuf[g][0][i] = a0 + bb;
            gbuf[g][1][i] = a1 + bb;
            gbuf[g][2][i] = a2 + bb;
            gbuf[g][3][i] = a3 + bb;
        }
    }
    __syncthreads();

    if (tid < 64) {
        const int bi = tid >> 4, ol = tid & 15;
        const int b = qb + bi, o = otile * 16 + ol;
        float gi = gbuf[0][bi][ol], gf = gbuf[1][bi][ol];
        float gg = gbuf[2][bi][ol], go = gbuf[3][bi][ol];
        float sc = sigmoidf_(gf) * sc1[b * OO + o] + sigmoidf_(gi) * tanhf(gg);
        float sh = sigmoidf_(go) * tanhf(sc);
        out_sc[b * OO + o] = sc;
        out_sh[b * OO + o] = sh;
    }
}

// ---------------- K2: scores + per-chunk softmax stats.
// wbuf[b,t] = exp(s - m_c) (0 for masked); pbuf[b,chunk] = (m_c, sum_exp_c).
__global__ __launch_bounds__(256) void scores_kernel(
    const float* __restrict__ hk, const float* __restrict__ mask,
    const float* __restrict__ sc, float* __restrict__ wbuf,
    float2* __restrict__ pbuf)
{
    const int b = blockIdx.y, chunk = blockIdx.x;
    const int tid = threadIdx.x;
    const int sg = tid >> 4, l = tid & 15;   // 16 subgroups x 16 lanes

    const float4 scA = *(const float4*)(sc + b * OO + l * 8);
    const float4 scB = *(const float4*)(sc + b * OO + l * 8 + 4);

    const int r0 = chunk * CHUNK_LEN + sg * 8;
    const float* mrow = mask + (size_t)b * TT + r0;
    const float* krow = hk + ((size_t)b * TT + r0) * OO;

    float s[8];
    bool val[8];
    #pragma unroll
    for (int i = 0; i < 8; ++i) {
        val[i] = (mrow[i] != 0.f);
        float4 a = make_float4(0.f, 0.f, 0.f, 0.f);
        float4 c2 = make_float4(0.f, 0.f, 0.f, 0.f);
        if (val[i]) {
            a  = *(const float4*)(krow + (size_t)i * OO + l * 8);
            c2 = *(const float4*)(krow + (size_t)i * OO + l * 8 + 4);
        }
        s[i] = a.x * scA.x + a.y * scA.y + a.z * scA.z + a.w * scA.w
             + c2.x * scB.x + c2.y * scB.y + c2.z * scB.z + c2.w * scB.w;
    }
    #pragma unroll
    for (int i = 0; i < 8; ++i) {
        s[i] += __shfl_xor(s[i], 8);
        s[i] += __shfl_xor(s[i], 4);
        s[i] += __shfl_xor(s[i], 2);
        s[i] += __shfl_xor(s[i], 1);
    }
    // all 16 lanes now hold all 8 row sums of this subgroup
    float msg = -INFINITY;
    #pragma unroll
    for (int i = 0; i < 8; ++i) if (val[i]) msg = fmaxf(msg, s[i]);

    __shared__ float sm[16], ssum[16];
    if (l == 0) sm[sg] = msg;
    __syncthreads();
    float mc = sm[0];
    #pragma unroll
    for (int i = 1; i < 16; ++i) mc = fmaxf(mc, sm[i]);

    float psum = 0.f;
    float e[8];
    #pragma unroll
    for (int i = 0; i < 8; ++i) {
        e[i] = val[i] ? __expf(s[i] - mc) : 0.f;   // mc=-inf only if no valid rows -> e=0
        psum += e[i];
    }
    if (l == 0) ssum[sg] = psum;
    float* wrow = wbuf + (size_t)b * TT + r0;
    #pragma unroll
    for (int i = 0; i < 8; ++i)
        if (l == i) wrow[i] = e[i];
    __syncthreads();
    if (tid == 0) {
        float S = 0.f;
        #pragma unroll
        for (int i = 0; i < 16; ++i) S += ssum[i];
        pbuf[(size_t)b * CHUNKS + chunk] = make_float2(mc, S);
    }
}

// ---------------- K3: normalized weighted sum over hv; per-chunk partial c.
__global__ __launch_bounds__(256) void wsum_kernel(
    const float* __restrict__ hv, const float* __restrict__ wbuf,
    const float2* __restrict__ pbuf, float* __restrict__ ws_c)
{
    const int b = blockIdx.y, chunk = blockIdx.x;
    const int tid = threadIdx.x;
    __shared__ float marr[CHUNKS], Sarr[CHUNKS];
    __shared__ float wsh[CHUNK_LEN];
    __shared__ float pacc[8][128];

    if (tid < CHUNKS) {
        float2 p = pbuf[(size_t)b * CHUNKS + tid];
        marr[tid] = p.x;
        Sarr[tid] = p.y;
    }
    __syncthreads();
    float M = marr[0];
    #pragma unroll
    for (int i = 1; i < CHUNKS; ++i) M = fmaxf(M, marr[i]);
    float S = 0.f;
    #pragma unroll
    for (int i = 0; i < CHUNKS; ++i) S += Sarr[i] * __expf(marr[i] - M);
    const float factor = __expf(marr[chunk] - M) / S;   // 0 for dead chunk

    if (tid < CHUNK_LEN)
        wsh[tid] = wbuf[(size_t)b * TT + chunk * CHUNK_LEN + tid] * factor;
    __syncthreads();

    const int o4 = tid & 31, rr = tid >> 5;   // 8 row-groups x 32 o-quads
    const float* vbase = hv + ((size_t)b * TT + chunk * CHUNK_LEN) * OO + o4 * 4;
    float4 acc = make_float4(0.f, 0.f, 0.f, 0.f);
    #pragma unroll 8
    for (int j = 0; j < 16; ++j) {
        const int r = rr + 8 * j;
        const float wr = wsh[r];
        if (wr != 0.f) {
            float4 v = *(const float4*)(vbase + (size_t)r * OO);
            acc.x += wr * v.x;
            acc.y += wr * v.y;
            acc.z += wr * v.z;
            acc.w += wr * v.w;
        }
    }
    *(float4*)&pacc[rr][o4 * 4] = acc;
    __syncthreads();

    if (tid < 128) {
        float s = 0.f;
        #pragma unroll
        for (int i = 0; i < 8; ++i) s += pacc[i][tid];
        ws_c[((size_t)b * CHUNKS + chunk) * OO + tid] = s;   // already normalized
    }
}

// ---------------- K4: combine chunk partials -> c, then MLP head + softmax.
__global__ __launch_bounds__(256) void final_kernel(
    const float* __restrict__ ws_c, const float* __restrict__ sh_in,
    const float* __restrict__ W1, const float* __restrict__ b1,
    const float* __restrict__ W2, const float* __restrict__ b2,
    const float* __restrict__ W3, const float* __restrict__ b3,
    float* __restrict__ out_p, float* __restrict__ out_c)
{
    const int b = blockIdx.x, tid = threadIdx.x;
    __shared__ float cbuf[128], shbuf[128], h1[LL], zz[LL], red2[2];

    if (tid < 128) {
        float s = 0.f;
        const float* base = ws_c + (size_t)b * CHUNKS * OO + tid;
        #pragma unroll
        for (int i = 0; i < CHUNKS; ++i) s += base[i * OO];
        cbuf[tid] = s;
        out_c[b * OO + tid] = s;
        shbuf[tid] = sh_in[b * OO + tid];
    }
    __syncthreads();

    const int o = tid >> 2, l2 = tid & 3;
    if (o < LL) {
        float a = 0.f;
        const float* w1r = W1 + o * OO;
        const float* w2r = W2 + o * OO;
        #pragma unroll 8
        for (int j = 0; j < 32; ++j) {
            int k = l2 + 4 * j;
            a += w1r[k] * shbuf[k] + w2r[k] * cbuf[k];
        }
        a += __shfl_xor(a, 1);
        a += __shfl_xor(a, 2);
        if (l2 == 0) h1[o] = fmaxf(a + b1[o] + b2[o], 0.f);
    }
    __syncthreads();

    if (o < LL) {
        float z = 0.f;
        const float* w3r = W3 + o * LL;
        for (int j = 0; j < 9; ++j) {
            int k = l2 + 4 * j;
            if (k < LL) z += w3r[k] * h1[k];
        }
        z += __shfl_xor(z, 1);
        z += __shfl_xor(z, 2);
        if (l2 == 0) zz[o] = z + b3[o];
    }
    __syncthreads();
    if (tid == 0) {
        float mm = zz[0];
        for (int i = 1; i < LL; i++) mm = fmaxf(mm, zz[i]);
        float ss = 0.f;
        for (int i = 0; i < LL; i++) ss += __expf(zz[i] - mm);
        red2[0] = mm; red2[1] = ss;
    }
    __syncthreads();
    if (tid < LL) out_p[b * LL + tid] = __expf(zz[tid] - red2[0]) / red2[1];
}

extern "C" void kernel_launch(void* const* d_in, const int* in_sizes, int n_in,
                              void* d_out, int out_size, void* d_ws, size_t ws_size,
                              hipStream_t stream) {
    (void)in_sizes; (void)n_in; (void)out_size; (void)ws_size;
    const float* hk   = (const float*)d_in[0];
    const float* hv   = (const float*)d_in[1];
    const float* y1   = (const float*)d_in[2];
    const float* c1   = (const float*)d_in[3];
    const float* sh1  = (const float*)d_in[4];
    const float* sc1  = (const float*)d_in[5];
    const float* mask = (const float*)d_in[6];
    const float* Wih  = (const float*)d_in[7];
    const float* bih  = (const float*)d_in[8];
    const float* Whh  = (const float*)d_in[9];
    const float* bhh  = (const float*)d_in[10];
    const float* W1   = (const float*)d_in[11];
    const float* b1   = (const float*)d_in[12];
    const float* W2   = (const float*)d_in[13];
    const float* b2   = (const float*)d_in[14];
    const float* W3   = (const float*)d_in[15];
    const float* b3   = (const float*)d_in[16];

    float* out    = (float*)d_out;        // [B, L]
    float* out_c  = out + BB * LL;        // [B, O]
    float* out_sh = out_c + BB * OO;      // [B, O]
    float* out_sc = out_sh + BB * OO;     // [B, O]

    float*  wbuf = (float*)d_ws;                         // [B, T] exp-weights (1 MB)
    float*  ws_c = wbuf + (size_t)BB * TT;               // [B, CHUNKS, O] partials (1 MB)
    float2* pbuf = (float2*)(ws_c + (size_t)BB * CHUNKS * OO);  // [B, CHUNKS] (m,S) 16 KB

    lstm_kernel<<<dim3(8, 32), 256, 0, stream>>>(y1, c1, sh1, sc1, Wih, bih, Whh, bhh,
                                                 out_sh, out_sc);
    scores_kernel<<<dim3(CHUNKS, BB), 256, 0, stream>>>(hk, mask, out_sc, wbuf, pbuf);
    wsum_kernel<<<dim3(CHUNKS, BB), 256, 0, stream>>>(hv, wbuf, pbuf, ws_c);
    final_kernel<<<BB, 256, 0, stream>>>(ws_c, out_sh, W1, b1, W2, b2, W3, b3,
                                         out, out_c);
}